// Round 1
// baseline (736.057 us; speedup 1.0000x reference)
//
#include <hip/hip_runtime.h>

#define HCC 128
#define NEG_SLOPE 0.2f
#define LS_NODES 64

// ---------------- edge_attr sum (for mean self-loop fill) ----------------
__global__ void ea_reduce_kernel(const float* __restrict__ ea, float* __restrict__ sum, int E) {
  float acc = 0.f;
  for (int i = blockIdx.x * blockDim.x + threadIdx.x; i < E; i += gridDim.x * blockDim.x)
    acc += ea[i];
  #pragma unroll
  for (int off = 32; off > 0; off >>= 1) acc += __shfl_down(acc, off);
  if ((threadIdx.x & 63) == 0) atomicAdd(sum, acc);
}

// ---------------- degree count over edges + self loops ----------------
__global__ void deg_count_kernel(const int* __restrict__ ei, int* __restrict__ deg, int E, int N) {
  int k = blockIdx.x * blockDim.x + threadIdx.x;
  if (k >= E + N) return;
  int t = (k < E) ? ei[E + k] : (k - E);
  atomicAdd(&deg[t], 1);
}

// ---------------- exclusive scan (single block, 1024 threads) ----------------
__global__ void scan_kernel(const int* __restrict__ deg, int* __restrict__ offs, int n) {
  __shared__ int wsum[16];
  int carry = 0;  // only thread 0's copy is meaningful
  for (int base = 0; base < n; base += 1024) {
    int i = base + (int)threadIdx.x;
    int v = (i < n) ? deg[i] : 0;
    int lane = threadIdx.x & 63, wid = threadIdx.x >> 6;
    int x = v;
    #pragma unroll
    for (int off = 1; off < 64; off <<= 1) {
      int y = __shfl_up(x, off);
      if (lane >= off) x += y;
    }
    if (lane == 63) wsum[wid] = x;
    __syncthreads();
    if (threadIdx.x == 0) {
      int run = carry;
      #pragma unroll
      for (int w2 = 0; w2 < 16; w2++) { int tv = wsum[w2]; wsum[w2] = run; run += tv; }
      carry = run;
    }
    __syncthreads();
    if (i < n) offs[i] = x - v + wsum[wid];
    __syncthreads();  // protect wsum before next chunk overwrites it
  }
  if (threadIdx.x == 0) offs[n] = carry;
}

// ---------------- scatter edges into CSR-by-target ----------------
__global__ void scatter_kernel(const int* __restrict__ ei, const float* __restrict__ ea,
                               const float* __restrict__ ea_sum, const int* __restrict__ offs,
                               int* __restrict__ cursor, int* __restrict__ csr_src,
                               float* __restrict__ csr_ea, int E, int N) {
  int k = blockIdx.x * blockDim.x + threadIdx.x;
  if (k >= E + N) return;
  int s, t; float v;
  if (k < E) { s = ei[k]; t = ei[E + k]; v = ea[k]; }
  else       { s = t = k - E; v = ea_sum[0] * (1.0f / (float)E); }
  int pos = offs[t] + atomicAdd(&cursor[t], 1);
  csr_src[pos] = s;
  csr_ea[pos] = v;
}

// ---------------- layer-1 transforms: x(N,1) -> xl, xr (N,128) ----------------
__global__ void l1_transform_kernel(const float* __restrict__ x,
    const float* __restrict__ Wl, const float* __restrict__ bl,
    const float* __restrict__ Wr, const float* __restrict__ br,
    float* __restrict__ xl, float* __restrict__ xr, int N) {
  int i = blockIdx.x * blockDim.x + threadIdx.x;
  int n = i >> 6, c = (i & 63) * 2;
  if (n >= N) return;
  float xv = x[n];
  float2 wl = *(const float2*)&Wl[c], blv = *(const float2*)&bl[c];
  float2 wr = *(const float2*)&Wr[c], brv = *(const float2*)&br[c];
  float2 ol = make_float2(fmaf(xv, wl.x, blv.x), fmaf(xv, wl.y, blv.y));
  float2 orr = make_float2(fmaf(xv, wr.x, brv.x), fmaf(xv, wr.y, brv.y));
  *(float2*)&xl[(size_t)n * HCC + c] = ol;
  *(float2*)&xr[(size_t)n * HCC + c] = orr;
}

// ---------------- GATv2 layer: one wave per target node ----------------
// channel c = 2*lane; lanes 0..31 = head0, lanes 32..63 = head1.
// Two-pass online softmax: pass1 max of alpha, pass2 recompute + weighted sum.
// Output = relu(segment_sum(xj * a) + bias), fully fused.
__global__ void gat_kernel(const float* __restrict__ xl, const float* __restrict__ xr,
    const int* __restrict__ offs, const int* __restrict__ csr_src,
    const float* __restrict__ csr_ea,
    const float* __restrict__ We, const float* __restrict__ att,
    const float* __restrict__ bias, float* __restrict__ outh, int N) {
  int w = (blockIdx.x * blockDim.x + threadIdx.x) >> 6;
  if (w >= N) return;
  int lane = threadIdx.x & 63;
  int c = lane * 2;
  int t = w;
  float2 xrv = *(const float2*)&xr[(size_t)t * HCC + c];
  float2 wev = *(const float2*)&We[c];
  float2 atv = *(const float2*)&att[c];
  int e0 = offs[t], e1 = offs[t + 1];

  float mx = -1e30f;
  for (int e = e0; e < e1; e++) {
    int s = csr_src[e]; float eav = csr_ea[e];
    float2 xj = *(const float2*)&xl[(size_t)s * HCC + c];
    float m0 = xrv.x + xj.x + eav * wev.x;
    float m1 = xrv.y + xj.y + eav * wev.y;
    m0 = m0 > 0.f ? m0 : NEG_SLOPE * m0;
    m1 = m1 > 0.f ? m1 : NEG_SLOPE * m1;
    float p = fmaf(m0, atv.x, m1 * atv.y);
    #pragma unroll
    for (int off = 1; off < 32; off <<= 1) p += __shfl_xor(p, off);
    mx = fmaxf(mx, p);
  }
  float den = 0.f, a0 = 0.f, a1 = 0.f;
  for (int e = e0; e < e1; e++) {
    int s = csr_src[e]; float eav = csr_ea[e];
    float2 xj = *(const float2*)&xl[(size_t)s * HCC + c];
    float m0 = xrv.x + xj.x + eav * wev.x;
    float m1 = xrv.y + xj.y + eav * wev.y;
    m0 = m0 > 0.f ? m0 : NEG_SLOPE * m0;
    m1 = m1 > 0.f ? m1 : NEG_SLOPE * m1;
    float p = fmaf(m0, atv.x, m1 * atv.y);
    #pragma unroll
    for (int off = 1; off < 32; off <<= 1) p += __shfl_xor(p, off);
    float wgt = expf(p - mx);
    den += wgt;
    a0 = fmaf(wgt, xj.x, a0);
    a1 = fmaf(wgt, xj.y, a1);
  }
  float inv = 1.0f / den;
  float2 bv = *(const float2*)&bias[c];
  float o0 = fmaxf(fmaf(a0, inv, bv.x), 0.f);
  float o1 = fmaxf(fmaf(a1, inv, bv.y), 0.f);
  *(float2*)&outh[(size_t)t * HCC + c] = make_float2(o0, o1);
}

// ---------------- layer-2 transforms: h1(N,128) @ {Wl,Wr}(128,128) ----------------
__global__ __launch_bounds__(256) void l2_transform_kernel(const float* __restrict__ h,
    const float* __restrict__ Wl, const float* __restrict__ bl,
    const float* __restrict__ Wr, const float* __restrict__ br,
    float* __restrict__ xl, float* __restrict__ xr, int N) {
  __shared__ float hs[16][HCC];
  __shared__ float Ws[2][32][HCC];
  int tid = threadIdx.x;
  int nbase = blockIdx.x * 16;
  for (int i = tid; i < 16 * 32; i += 256) {
    int nr = i >> 5, col = (i & 31) * 4;
    int gn = nbase + nr;
    float4 v = (gn < N) ? *(const float4*)&h[(size_t)gn * HCC + col] : make_float4(0,0,0,0);
    *(float4*)&hs[nr][col] = v;
  }
  int slot = tid >> 5;
  int c0 = (tid & 31) * 4;
  float acc[2][8];
  #pragma unroll
  for (int s = 0; s < 2; s++)
    #pragma unroll
    for (int q = 0; q < 8; q++) acc[s][q] = 0.f;

  for (int kb = 0; kb < 4; kb++) {
    __syncthreads();
    for (int i = tid; i < 2048; i += 256) {
      int mat = i >> 10;
      int idx = i & 1023;
      int krow = idx >> 5, col = (idx & 31) * 4;
      const float* src = mat ? Wr : Wl;
      *(float4*)&Ws[mat][krow][col] = *(const float4*)&src[(size_t)(kb * 32 + krow) * HCC + col];
    }
    __syncthreads();
    for (int k2 = 0; k2 < 32; k2++) {
      float4 wl4 = *(const float4*)&Ws[0][k2][c0];
      float4 wr4 = *(const float4*)&Ws[1][k2][c0];
      int kk = kb * 32 + k2;
      #pragma unroll
      for (int s = 0; s < 2; s++) {
        float hv = hs[slot + 8 * s][kk];
        acc[s][0] = fmaf(hv, wl4.x, acc[s][0]);
        acc[s][1] = fmaf(hv, wl4.y, acc[s][1]);
        acc[s][2] = fmaf(hv, wl4.z, acc[s][2]);
        acc[s][3] = fmaf(hv, wl4.w, acc[s][3]);
        acc[s][4] = fmaf(hv, wr4.x, acc[s][4]);
        acc[s][5] = fmaf(hv, wr4.y, acc[s][5]);
        acc[s][6] = fmaf(hv, wr4.z, acc[s][6]);
        acc[s][7] = fmaf(hv, wr4.w, acc[s][7]);
      }
    }
  }
  float4 blv = *(const float4*)&bl[c0];
  float4 brv = *(const float4*)&br[c0];
  #pragma unroll
  for (int s = 0; s < 2; s++) {
    int gn = nbase + slot + 8 * s;
    if (gn < N) {
      float4 o1 = make_float4(acc[s][0] + blv.x, acc[s][1] + blv.y, acc[s][2] + blv.z, acc[s][3] + blv.w);
      float4 o2 = make_float4(acc[s][4] + brv.x, acc[s][5] + brv.y, acc[s][6] + brv.z, acc[s][7] + brv.w);
      *(float4*)&xl[(size_t)gn * HCC + c0] = o1;
      *(float4*)&xr[(size_t)gn * HCC + c0] = o2;
    }
  }
}

// ---------------- msg_emb = message @ fc1_W + fc1_b  (B x 128) ----------------
__global__ void msg_gemm_kernel(const float* __restrict__ msg, const float* __restrict__ W,
                                const float* __restrict__ b, float* __restrict__ memb) {
  int r = blockIdx.x, c = threadIdx.x;
  const float* mrow = &msg[(size_t)r * HCC];
  float acc = b[c];
  #pragma unroll 8
  for (int k = 0; k < HCC; k++) acc = fmaf(mrow[k], W[(size_t)k * HCC + c], acc);
  memb[(size_t)r * HCC + c] = acc;
}

// ---------------- logits = h @ membT; row softmax; write out ----------------
// 512 threads: tid = 2*b + half; each thread holds 64 msg_emb values in regs.
__global__ __launch_bounds__(512) void logits_softmax_kernel(
    const float* __restrict__ h, const float* __restrict__ memb,
    float* __restrict__ out, int N) {
  __shared__ float hs[LS_NODES][HCC];
  __shared__ float red[16];
  int tid = threadIdx.x;
  int b = tid >> 1, half = tid & 1;
  float mreg[64];
  {
    const float* mp = &memb[(size_t)b * HCC + half * 64];
    #pragma unroll
    for (int j = 0; j < 16; j++) {
      float4 v = *(const float4*)&mp[j * 4];
      mreg[4*j] = v.x; mreg[4*j+1] = v.y; mreg[4*j+2] = v.z; mreg[4*j+3] = v.w;
    }
  }
  int nbase = blockIdx.x * LS_NODES;
  for (int i = tid; i < LS_NODES * 32; i += 512) {
    int nr = i >> 5, col = (i & 31) * 4;
    int gn = nbase + nr;
    float4 v = (gn < N) ? *(const float4*)&h[(size_t)gn * HCC + col] : make_float4(0,0,0,0);
    *(float4*)&hs[nr][col] = v;
  }
  __syncthreads();
  int wid = tid >> 6, lane = tid & 63;
  int nmax = (N - nbase < LS_NODES) ? (N - nbase) : LS_NODES;
  for (int nl = 0; nl < nmax; nl++) {
    const float* hp = &hs[nl][half * 64];
    float a0 = 0.f, a1 = 0.f, a2 = 0.f, a3 = 0.f;
    #pragma unroll
    for (int j = 0; j < 64; j += 4) {
      a0 = fmaf(mreg[j],     hp[j],     a0);
      a1 = fmaf(mreg[j + 1], hp[j + 1], a1);
      a2 = fmaf(mreg[j + 2], hp[j + 2], a2);
      a3 = fmaf(mreg[j + 3], hp[j + 3], a3);
    }
    float p = (a0 + a1) + (a2 + a3);
    p += __shfl_xor(p, 1);  // combine the two k-halves; pair now holds full logit
    float mx = p;
    #pragma unroll
    for (int off = 2; off < 64; off <<= 1) mx = fmaxf(mx, __shfl_xor(mx, off));
    if (lane == 0) red[wid] = mx;
    __syncthreads();
    float bmx = red[0];
    #pragma unroll
    for (int w2 = 1; w2 < 8; w2++) bmx = fmaxf(bmx, red[w2]);
    float ex = expf(p - bmx);
    float sv = half ? 0.f : ex;
    #pragma unroll
    for (int off = 1; off < 64; off <<= 1) sv += __shfl_xor(sv, off);
    if (lane == 0) red[8 + wid] = sv;
    __syncthreads();
    float bsum = red[8];
    #pragma unroll
    for (int w2 = 1; w2 < 8; w2++) bsum += red[8 + w2];
    if (half == 0) out[(size_t)(nbase + nl) * 256 + b] = ex / bsum;
  }
}

extern "C" void kernel_launch(void* const* d_in, const int* in_sizes, int n_in,
                              void* d_out, int out_size, void* d_ws, size_t ws_size,
                              hipStream_t stream) {
  (void)n_in; (void)out_size; (void)ws_size;
  const float* message  = (const float*)d_in[0];
  const float* x        = (const float*)d_in[1];
  const float* edge_attr= (const float*)d_in[2];
  const float* c1_Wl   = (const float*)d_in[3];
  const float* c1_bl   = (const float*)d_in[4];
  const float* c1_Wr   = (const float*)d_in[5];
  const float* c1_br   = (const float*)d_in[6];
  const float* c1_We   = (const float*)d_in[7];
  const float* c1_att  = (const float*)d_in[8];
  const float* c1_bias = (const float*)d_in[9];
  const float* c2_Wl   = (const float*)d_in[10];
  const float* c2_bl   = (const float*)d_in[11];
  const float* c2_Wr   = (const float*)d_in[12];
  const float* c2_br   = (const float*)d_in[13];
  const float* c2_We   = (const float*)d_in[14];
  const float* c2_att  = (const float*)d_in[15];
  const float* c2_bias = (const float*)d_in[16];
  const float* fc1_W   = (const float*)d_in[17];
  const float* fc1_b   = (const float*)d_in[18];
  const int* edge_index = (const int*)d_in[19];

  const int N = in_sizes[1];          // 50000 (x is N x 1)
  const int E = in_sizes[2];          // 500000
  const int Et = E + N;
  const int B = in_sizes[0] / HCC;    // 256
  float* out = (float*)d_out;

  char* wsb = (char*)d_ws;
  size_t woff = 0;
  auto alloc = [&](size_t bytes) -> void* {
    void* p = wsb + woff;
    woff += (bytes + 255) & ~(size_t)255;
    return p;
  };
  float* xl     = (float*)alloc((size_t)N * HCC * 4);
  float* xr     = (float*)alloc((size_t)N * HCC * 4);
  float* hb     = (float*)alloc((size_t)N * HCC * 4);
  float* memb   = (float*)alloc((size_t)B * HCC * 4);
  float* ea_sum = (float*)alloc(256);
  int* deg      = (int*)alloc((size_t)N * 4);
  int* offs     = (int*)alloc((size_t)(N + 1) * 4);
  int* cursor   = (int*)alloc((size_t)N * 4);
  int* csr_src  = (int*)alloc((size_t)Et * 4);
  float* csr_ea = (float*)alloc((size_t)Et * 4);

  hipMemsetAsync(ea_sum, 0, 4, stream);
  hipMemsetAsync(deg, 0, (size_t)N * 4, stream);
  hipMemsetAsync(cursor, 0, (size_t)N * 4, stream);

  ea_reduce_kernel<<<256, 256, 0, stream>>>(edge_attr, ea_sum, E);
  deg_count_kernel<<<(Et + 255) / 256, 256, 0, stream>>>(edge_index, deg, E, N);
  scan_kernel<<<1, 1024, 0, stream>>>(deg, offs, N);
  scatter_kernel<<<(Et + 255) / 256, 256, 0, stream>>>(edge_index, edge_attr, ea_sum,
                                                       offs, cursor, csr_src, csr_ea, E, N);
  l1_transform_kernel<<<(N * 64 + 255) / 256, 256, 0, stream>>>(x, c1_Wl, c1_bl, c1_Wr, c1_br,
                                                                xl, xr, N);
  gat_kernel<<<(N + 3) / 4, 256, 0, stream>>>(xl, xr, offs, csr_src, csr_ea,
                                              c1_We, c1_att, c1_bias, hb, N);
  l2_transform_kernel<<<(N + 15) / 16, 256, 0, stream>>>(hb, c2_Wl, c2_bl, c2_Wr, c2_br,
                                                         xl, xr, N);
  gat_kernel<<<(N + 3) / 4, 256, 0, stream>>>(xl, xr, offs, csr_src, csr_ea,
                                              c2_We, c2_att, c2_bias, hb, N);
  msg_gemm_kernel<<<B, HCC, 0, stream>>>(message, fc1_W, fc1_b, memb);
  logits_softmax_kernel<<<(N + LS_NODES - 1) / LS_NODES, 512, 0, stream>>>(hb, memb, out, N);
}

// Round 2
// 587.736 us; speedup vs baseline: 1.2524x; 1.2524x over previous
//
#include <hip/hip_runtime.h>

#define HCC 128
#define NEG_SLOPE 0.2f

// ---------------- edge_attr sum (for mean self-loop fill) ----------------
__global__ void ea_reduce_kernel(const float* __restrict__ ea, float* __restrict__ sum, int E) {
  float acc = 0.f;
  for (int i = blockIdx.x * blockDim.x + threadIdx.x; i < E; i += gridDim.x * blockDim.x)
    acc += ea[i];
  #pragma unroll
  for (int off = 32; off > 0; off >>= 1) acc += __shfl_down(acc, off);
  if ((threadIdx.x & 63) == 0) atomicAdd(sum, acc);
}

// ---------------- degree count over edges + self loops ----------------
__global__ void deg_count_kernel(const int* __restrict__ ei, int* __restrict__ deg, int E, int N) {
  int k = blockIdx.x * blockDim.x + threadIdx.x;
  if (k >= E + N) return;
  int t = (k < E) ? ei[E + k] : (k - E);
  atomicAdd(&deg[t], 1);
}

// ---------------- exclusive scan (single block, 1024 threads) ----------------
__global__ void scan_kernel(const int* __restrict__ deg, int* __restrict__ offs, int n) {
  __shared__ int wsum[16];
  int carry = 0;  // only thread 0's copy is meaningful
  for (int base = 0; base < n; base += 1024) {
    int i = base + (int)threadIdx.x;
    int v = (i < n) ? deg[i] : 0;
    int lane = threadIdx.x & 63, wid = threadIdx.x >> 6;
    int x = v;
    #pragma unroll
    for (int off = 1; off < 64; off <<= 1) {
      int y = __shfl_up(x, off);
      if (lane >= off) x += y;
    }
    if (lane == 63) wsum[wid] = x;
    __syncthreads();
    if (threadIdx.x == 0) {
      int run = carry;
      #pragma unroll
      for (int w2 = 0; w2 < 16; w2++) { int tv = wsum[w2]; wsum[w2] = run; run += tv; }
      carry = run;
    }
    __syncthreads();
    if (i < n) offs[i] = x - v + wsum[wid];
    __syncthreads();  // protect wsum before next chunk overwrites it
  }
  if (threadIdx.x == 0) offs[n] = carry;
}

// ---------------- scatter edges into CSR-by-target ----------------
__global__ void scatter_kernel(const int* __restrict__ ei, const float* __restrict__ ea,
                               const float* __restrict__ ea_sum, const int* __restrict__ offs,
                               int* __restrict__ cursor, int* __restrict__ csr_src,
                               float* __restrict__ csr_ea, int E, int N) {
  int k = blockIdx.x * blockDim.x + threadIdx.x;
  if (k >= E + N) return;
  int s, t; float v;
  if (k < E) { s = ei[k]; t = ei[E + k]; v = ea[k]; }
  else       { s = t = k - E; v = ea_sum[0] * (1.0f / (float)E); }
  int pos = offs[t] + atomicAdd(&cursor[t], 1);
  csr_src[pos] = s;
  csr_ea[pos] = v;
}

// ---------------- layer-1 transforms: x(N,1) -> xl, xr (N,128) ----------------
__global__ void l1_transform_kernel(const float* __restrict__ x,
    const float* __restrict__ Wl, const float* __restrict__ bl,
    const float* __restrict__ Wr, const float* __restrict__ br,
    float* __restrict__ xl, float* __restrict__ xr, int N) {
  int i = blockIdx.x * blockDim.x + threadIdx.x;
  int n = i >> 6, c = (i & 63) * 2;
  if (n >= N) return;
  float xv = x[n];
  float2 wl = *(const float2*)&Wl[c], blv = *(const float2*)&bl[c];
  float2 wr = *(const float2*)&Wr[c], brv = *(const float2*)&br[c];
  float2 ol = make_float2(fmaf(xv, wl.x, blv.x), fmaf(xv, wl.y, blv.y));
  float2 orr = make_float2(fmaf(xv, wr.x, brv.x), fmaf(xv, wr.y, brv.y));
  *(float2*)&xl[(size_t)n * HCC + c] = ol;
  *(float2*)&xr[(size_t)n * HCC + c] = orr;
}

// ---------------- GATv2 layer: one wave per target node ----------------
__global__ void gat_kernel(const float* __restrict__ xl, const float* __restrict__ xr,
    const int* __restrict__ offs, const int* __restrict__ csr_src,
    const float* __restrict__ csr_ea,
    const float* __restrict__ We, const float* __restrict__ att,
    const float* __restrict__ bias, float* __restrict__ outh, int N) {
  int w = (blockIdx.x * blockDim.x + threadIdx.x) >> 6;
  if (w >= N) return;
  int lane = threadIdx.x & 63;
  int c = lane * 2;
  int t = w;
  float2 xrv = *(const float2*)&xr[(size_t)t * HCC + c];
  float2 wev = *(const float2*)&We[c];
  float2 atv = *(const float2*)&att[c];
  int e0 = offs[t], e1 = offs[t + 1];

  float mx = -1e30f;
  for (int e = e0; e < e1; e++) {
    int s = csr_src[e]; float eav = csr_ea[e];
    float2 xj = *(const float2*)&xl[(size_t)s * HCC + c];
    float m0 = xrv.x + xj.x + eav * wev.x;
    float m1 = xrv.y + xj.y + eav * wev.y;
    m0 = m0 > 0.f ? m0 : NEG_SLOPE * m0;
    m1 = m1 > 0.f ? m1 : NEG_SLOPE * m1;
    float p = fmaf(m0, atv.x, m1 * atv.y);
    #pragma unroll
    for (int off = 1; off < 32; off <<= 1) p += __shfl_xor(p, off);
    mx = fmaxf(mx, p);
  }
  float den = 0.f, a0 = 0.f, a1 = 0.f;
  for (int e = e0; e < e1; e++) {
    int s = csr_src[e]; float eav = csr_ea[e];
    float2 xj = *(const float2*)&xl[(size_t)s * HCC + c];
    float m0 = xrv.x + xj.x + eav * wev.x;
    float m1 = xrv.y + xj.y + eav * wev.y;
    m0 = m0 > 0.f ? m0 : NEG_SLOPE * m0;
    m1 = m1 > 0.f ? m1 : NEG_SLOPE * m1;
    float p = fmaf(m0, atv.x, m1 * atv.y);
    #pragma unroll
    for (int off = 1; off < 32; off <<= 1) p += __shfl_xor(p, off);
    float wgt = expf(p - mx);
    den += wgt;
    a0 = fmaf(wgt, xj.x, a0);
    a1 = fmaf(wgt, xj.y, a1);
  }
  float inv = 1.0f / den;
  float2 bv = *(const float2*)&bias[c];
  float o0 = fmaxf(fmaf(a0, inv, bv.x), 0.f);
  float o1 = fmaxf(fmaf(a1, inv, bv.y), 0.f);
  *(float2*)&outh[(size_t)t * HCC + c] = make_float2(o0, o1);
}

// ---------------- layer-2 transforms: h1(N,128) @ {Wl,Wr}(128,128) ----------------
__global__ __launch_bounds__(256) void l2_transform_kernel(const float* __restrict__ h,
    const float* __restrict__ Wl, const float* __restrict__ bl,
    const float* __restrict__ Wr, const float* __restrict__ br,
    float* __restrict__ xl, float* __restrict__ xr, int N) {
  __shared__ float hs[16][HCC];
  __shared__ float Ws[2][32][HCC];
  int tid = threadIdx.x;
  int nbase = blockIdx.x * 16;
  for (int i = tid; i < 16 * 32; i += 256) {
    int nr = i >> 5, col = (i & 31) * 4;
    int gn = nbase + nr;
    float4 v = (gn < N) ? *(const float4*)&h[(size_t)gn * HCC + col] : make_float4(0,0,0,0);
    *(float4*)&hs[nr][col] = v;
  }
  int slot = tid >> 5;
  int c0 = (tid & 31) * 4;
  float acc[2][8];
  #pragma unroll
  for (int s = 0; s < 2; s++)
    #pragma unroll
    for (int q = 0; q < 8; q++) acc[s][q] = 0.f;

  for (int kb = 0; kb < 4; kb++) {
    __syncthreads();
    for (int i = tid; i < 2048; i += 256) {
      int mat = i >> 10;
      int idx = i & 1023;
      int krow = idx >> 5, col = (idx & 31) * 4;
      const float* src = mat ? Wr : Wl;
      *(float4*)&Ws[mat][krow][col] = *(const float4*)&src[(size_t)(kb * 32 + krow) * HCC + col];
    }
    __syncthreads();
    for (int k2 = 0; k2 < 32; k2++) {
      float4 wl4 = *(const float4*)&Ws[0][k2][c0];
      float4 wr4 = *(const float4*)&Ws[1][k2][c0];
      int kk = kb * 32 + k2;
      #pragma unroll
      for (int s = 0; s < 2; s++) {
        float hv = hs[slot + 8 * s][kk];
        acc[s][0] = fmaf(hv, wl4.x, acc[s][0]);
        acc[s][1] = fmaf(hv, wl4.y, acc[s][1]);
        acc[s][2] = fmaf(hv, wl4.z, acc[s][2]);
        acc[s][3] = fmaf(hv, wl4.w, acc[s][3]);
        acc[s][4] = fmaf(hv, wr4.x, acc[s][4]);
        acc[s][5] = fmaf(hv, wr4.y, acc[s][5]);
        acc[s][6] = fmaf(hv, wr4.z, acc[s][6]);
        acc[s][7] = fmaf(hv, wr4.w, acc[s][7]);
      }
    }
  }
  float4 blv = *(const float4*)&bl[c0];
  float4 brv = *(const float4*)&br[c0];
  #pragma unroll
  for (int s = 0; s < 2; s++) {
    int gn = nbase + slot + 8 * s;
    if (gn < N) {
      float4 o1 = make_float4(acc[s][0] + blv.x, acc[s][1] + blv.y, acc[s][2] + blv.z, acc[s][3] + blv.w);
      float4 o2 = make_float4(acc[s][4] + brv.x, acc[s][5] + brv.y, acc[s][6] + brv.z, acc[s][7] + brv.w);
      *(float4*)&xl[(size_t)gn * HCC + c0] = o1;
      *(float4*)&xr[(size_t)gn * HCC + c0] = o2;
    }
  }
}

// ---------------- msg_emb^T = (message @ fc1_W + fc1_b)^T  -> [128][256] ----------------
__global__ void msg_gemm_kernel(const float* __restrict__ msg, const float* __restrict__ W,
                                const float* __restrict__ b, float* __restrict__ memb_t) {
  int r = blockIdx.x, c = threadIdx.x;  // r = message index (0..255), c = out channel (0..127)
  const float* mrow = &msg[(size_t)r * HCC];
  float acc = b[c];
  #pragma unroll 8
  for (int k = 0; k < HCC; k++) acc = fmaf(mrow[k], W[(size_t)k * HCC + c], acc);
  memb_t[(size_t)c * 256 + r] = acc;
}

// ---------------- logits = h @ memb^T; row softmax ----------------
// Block: 64 nodes x 256 msgs. 256 threads: ty=tid>>5 owns 8 nodes, tx=tid&31
// owns msg cols {j*32+tx}. 8x8 register tile per thread (8192 FMA/thread).
// Softmax reduces across tx only -> pure 32-lane shuffles, zero barriers.
__global__ __launch_bounds__(256) void logits_softmax_kernel(
    const float* __restrict__ h, const float* __restrict__ memb_t,
    float* __restrict__ out, int N) {
  __shared__ float hs[64][HCC];   // 32 KB
  __shared__ float ms[32][256];   // 32 KB  (k-chunk of memb_t)
  int tid = threadIdx.x;
  int nbase = blockIdx.x * 64;
  for (int i = tid; i < 64 * 32; i += 256) {
    int nr = i >> 5, col = (i & 31) * 4;
    int gn = nbase + nr;
    float4 v = (gn < N) ? *(const float4*)&h[(size_t)gn * HCC + col] : make_float4(0, 0, 0, 0);
    *(float4*)&hs[nr][col] = v;
  }
  int ty = tid >> 5, tx = tid & 31;
  float acc[8][8];
  #pragma unroll
  for (int i = 0; i < 8; i++)
    #pragma unroll
    for (int j = 0; j < 8; j++) acc[i][j] = 0.f;

  for (int kb = 0; kb < 4; kb++) {
    __syncthreads();  // iter0: hs staged; later: prior reads of ms done
    for (int i = tid; i < 2048; i += 256) {
      int kr = i >> 6, col = (i & 63) * 4;
      *(float4*)&ms[kr][col] = *(const float4*)&memb_t[(size_t)(kb * 32 + kr) * 256 + col];
    }
    __syncthreads();
    for (int kk = 0; kk < 32; kk += 4) {
      float4 a[8];
      #pragma unroll
      for (int i = 0; i < 8; i++) a[i] = *(const float4*)&hs[ty * 8 + i][kb * 32 + kk];
      #pragma unroll
      for (int q = 0; q < 4; q++) {
        float bv[8];
        #pragma unroll
        for (int j = 0; j < 8; j++) bv[j] = ms[kk + q][j * 32 + tx];
        #pragma unroll
        for (int i = 0; i < 8; i++) {
          float av = (q == 0) ? a[i].x : (q == 1) ? a[i].y : (q == 2) ? a[i].z : a[i].w;
          #pragma unroll
          for (int j = 0; j < 8; j++) acc[i][j] = fmaf(av, bv[j], acc[i][j]);
        }
      }
    }
  }

  // per-node softmax over 256 cols: local 8 + shuffle over 32 lanes (same ty group)
  #pragma unroll
  for (int i = 0; i < 8; i++) {
    int gn = nbase + ty * 8 + i;
    float m = acc[i][0];
    #pragma unroll
    for (int j = 1; j < 8; j++) m = fmaxf(m, acc[i][j]);
    #pragma unroll
    for (int off = 1; off < 32; off <<= 1) m = fmaxf(m, __shfl_xor(m, off));
    float e[8], s = 0.f;
    #pragma unroll
    for (int j = 0; j < 8; j++) { e[j] = expf(acc[i][j] - m); s += e[j]; }
    #pragma unroll
    for (int off = 1; off < 32; off <<= 1) s += __shfl_xor(s, off);
    float inv = 1.0f / s;
    if (gn < N) {
      #pragma unroll
      for (int j = 0; j < 8; j++) out[(size_t)gn * 256 + j * 32 + tx] = e[j] * inv;
    }
  }
}

extern "C" void kernel_launch(void* const* d_in, const int* in_sizes, int n_in,
                              void* d_out, int out_size, void* d_ws, size_t ws_size,
                              hipStream_t stream) {
  (void)n_in; (void)out_size; (void)ws_size;
  const float* message  = (const float*)d_in[0];
  const float* x        = (const float*)d_in[1];
  const float* edge_attr= (const float*)d_in[2];
  const float* c1_Wl   = (const float*)d_in[3];
  const float* c1_bl   = (const float*)d_in[4];
  const float* c1_Wr   = (const float*)d_in[5];
  const float* c1_br   = (const float*)d_in[6];
  const float* c1_We   = (const float*)d_in[7];
  const float* c1_att  = (const float*)d_in[8];
  const float* c1_bias = (const float*)d_in[9];
  const float* c2_Wl   = (const float*)d_in[10];
  const float* c2_bl   = (const float*)d_in[11];
  const float* c2_Wr   = (const float*)d_in[12];
  const float* c2_br   = (const float*)d_in[13];
  const float* c2_We   = (const float*)d_in[14];
  const float* c2_att  = (const float*)d_in[15];
  const float* c2_bias = (const float*)d_in[16];
  const float* fc1_W   = (const float*)d_in[17];
  const float* fc1_b   = (const float*)d_in[18];
  const int* edge_index = (const int*)d_in[19];

  const int N = in_sizes[1];          // 50000
  const int E = in_sizes[2];          // 500000
  const int Et = E + N;
  const int B = in_sizes[0] / HCC;    // 256
  float* out = (float*)d_out;

  char* wsb = (char*)d_ws;
  size_t woff = 0;
  auto alloc = [&](size_t bytes) -> void* {
    void* p = wsb + woff;
    woff += (bytes + 255) & ~(size_t)255;
    return p;
  };
  float* xl     = (float*)alloc((size_t)N * HCC * 4);
  float* xr     = (float*)alloc((size_t)N * HCC * 4);
  float* hb     = (float*)alloc((size_t)N * HCC * 4);
  float* memb_t = (float*)alloc((size_t)B * HCC * 4);
  float* ea_sum = (float*)alloc(256);
  int* deg      = (int*)alloc((size_t)N * 4);
  int* offs     = (int*)alloc((size_t)(N + 1) * 4);
  int* cursor   = (int*)alloc((size_t)N * 4);
  int* csr_src  = (int*)alloc((size_t)Et * 4);
  float* csr_ea = (float*)alloc((size_t)Et * 4);

  hipMemsetAsync(ea_sum, 0, 4, stream);
  hipMemsetAsync(deg, 0, (size_t)N * 4, stream);
  hipMemsetAsync(cursor, 0, (size_t)N * 4, stream);

  ea_reduce_kernel<<<256, 256, 0, stream>>>(edge_attr, ea_sum, E);
  deg_count_kernel<<<(Et + 255) / 256, 256, 0, stream>>>(edge_index, deg, E, N);
  scan_kernel<<<1, 1024, 0, stream>>>(deg, offs, N);
  scatter_kernel<<<(Et + 255) / 256, 256, 0, stream>>>(edge_index, edge_attr, ea_sum,
                                                       offs, cursor, csr_src, csr_ea, E, N);
  l1_transform_kernel<<<(N * 64 + 255) / 256, 256, 0, stream>>>(x, c1_Wl, c1_bl, c1_Wr, c1_br,
                                                                xl, xr, N);
  gat_kernel<<<(N + 3) / 4, 256, 0, stream>>>(xl, xr, offs, csr_src, csr_ea,
                                              c1_We, c1_att, c1_bias, hb, N);
  l2_transform_kernel<<<(N + 15) / 16, 256, 0, stream>>>(hb, c2_Wl, c2_bl, c2_Wr, c2_br,
                                                         xl, xr, N);
  gat_kernel<<<(N + 3) / 4, 256, 0, stream>>>(xl, xr, offs, csr_src, csr_ea,
                                              c2_We, c2_att, c2_bias, hb, N);
  msg_gemm_kernel<<<B, HCC, 0, stream>>>(message, fc1_W, fc1_b, memb_t);
  logits_softmax_kernel<<<(N + 63) / 64, 256, 0, stream>>>(hb, memb_t, out, N);
}

// Round 3
// 388.631 us; speedup vs baseline: 1.8940x; 1.5123x over previous
//
#include <hip/hip_runtime.h>

#define HCC 128
#define NEG_SLOPE 0.2f

// ---------------- edge_attr sum (for mean self-loop fill) ----------------
__global__ void ea_reduce_kernel(const float* __restrict__ ea, float* __restrict__ sum, int E) {
  float acc = 0.f;
  for (int i = blockIdx.x * blockDim.x + threadIdx.x; i < E; i += gridDim.x * blockDim.x)
    acc += ea[i];
  #pragma unroll
  for (int off = 32; off > 0; off >>= 1) acc += __shfl_down(acc, off);
  if ((threadIdx.x & 63) == 0) atomicAdd(sum, acc);
}

// ---------------- degree count over edges + self loops ----------------
__global__ void deg_count_kernel(const int* __restrict__ ei, int* __restrict__ deg, int E, int N) {
  int k = blockIdx.x * blockDim.x + threadIdx.x;
  if (k >= E + N) return;
  int t = (k < E) ? ei[E + k] : (k - E);
  atomicAdd(&deg[t], 1);
}

// ---------------- exclusive scan (single block, 1024 threads) ----------------
__global__ void scan_kernel(const int* __restrict__ deg, int* __restrict__ offs, int n) {
  __shared__ int wsum[16];
  int carry = 0;  // only thread 0's copy is meaningful
  for (int base = 0; base < n; base += 1024) {
    int i = base + (int)threadIdx.x;
    int v = (i < n) ? deg[i] : 0;
    int lane = threadIdx.x & 63, wid = threadIdx.x >> 6;
    int x = v;
    #pragma unroll
    for (int off = 1; off < 64; off <<= 1) {
      int y = __shfl_up(x, off);
      if (lane >= off) x += y;
    }
    if (lane == 63) wsum[wid] = x;
    __syncthreads();
    if (threadIdx.x == 0) {
      int run = carry;
      #pragma unroll
      for (int w2 = 0; w2 < 16; w2++) { int tv = wsum[w2]; wsum[w2] = run; run += tv; }
      carry = run;
    }
    __syncthreads();
    if (i < n) offs[i] = x - v + wsum[wid];
    __syncthreads();  // protect wsum before next chunk overwrites it
  }
  if (threadIdx.x == 0) offs[n] = carry;
}

// ---------------- scatter edges into CSR-by-target ----------------
__global__ void scatter_kernel(const int* __restrict__ ei, const float* __restrict__ ea,
                               const float* __restrict__ ea_sum, const int* __restrict__ offs,
                               int* __restrict__ cursor, int* __restrict__ csr_src,
                               float* __restrict__ csr_ea, int E, int N) {
  int k = blockIdx.x * blockDim.x + threadIdx.x;
  if (k >= E + N) return;
  int s, t; float v;
  if (k < E) { s = ei[k]; t = ei[E + k]; v = ea[k]; }
  else       { s = t = k - E; v = ea_sum[0] * (1.0f / (float)E); }
  int pos = offs[t] + atomicAdd(&cursor[t], 1);
  csr_src[pos] = s;
  csr_ea[pos] = v;
}

// ---------------- GATv2 layer 1, specialized for x of shape (N,1) ----------------
// xl[s] = x_s*Wl + bl is rank-1, so: attention logit needs only scalars
// (x_s, x_t, ea), and since sum_e a_e = 1 per head the aggregation collapses:
// out[c] = Wl[c]*(sum_e a_e x_s) + bl[c] + bias[c]. One wave per node,
// online softmax, 12 B gathered per edge (all L2-resident).
__global__ void gat1_kernel(const float* __restrict__ x,
    const int* __restrict__ offs, const int* __restrict__ csr_src,
    const float* __restrict__ csr_ea,
    const float* __restrict__ Wl, const float* __restrict__ bl,
    const float* __restrict__ Wr, const float* __restrict__ br,
    const float* __restrict__ We, const float* __restrict__ att,
    const float* __restrict__ bias, float* __restrict__ outh, int N) {
  int t = (blockIdx.x * blockDim.x + threadIdx.x) >> 6;
  if (t >= N) return;
  int lane = threadIdx.x & 63;
  int c = lane * 2;
  float2 wl = *(const float2*)&Wl[c];
  float2 wr = *(const float2*)&Wr[c];
  float2 we = *(const float2*)&We[c];
  float2 at = *(const float2*)&att[c];
  float2 bl2 = *(const float2*)&bl[c];
  float2 br2 = *(const float2*)&br[c];
  float xt = x[t];
  // m_c = x_t*Wr[c] + br[c] + bl[c] + x_s*Wl[c] + ea*We[c]
  float base0 = fmaf(xt, wr.x, br2.x + bl2.x);
  float base1 = fmaf(xt, wr.y, br2.y + bl2.y);
  int e0 = offs[t], e1 = offs[t + 1];

  float mx = -1e30f, den = 0.f, S1 = 0.f;
  float ean = csr_ea[e0];
  float xsn = x[csr_src[e0]];
  for (int e = e0; e < e1; e++) {
    float xs = xsn, eav = ean;
    if (e + 1 < e1) {             // prefetch next edge's scalars
      int s2 = csr_src[e + 1];
      ean = csr_ea[e + 1];
      xsn = x[s2];
    }
    float m0 = fmaf(xs, wl.x, fmaf(eav, we.x, base0));
    float m1 = fmaf(xs, wl.y, fmaf(eav, we.y, base1));
    m0 = m0 > 0.f ? m0 : NEG_SLOPE * m0;
    m1 = m1 > 0.f ? m1 : NEG_SLOPE * m1;
    float p = fmaf(m0, at.x, m1 * at.y);
    #pragma unroll
    for (int off = 1; off < 32; off <<= 1) p += __shfl_xor(p, off);
    // online softmax, single exp per edge
    float d = p - mx;
    float ed = __expf(-fabsf(d));
    float scale = d > 0.f ? ed : 1.f;
    float wgt = d > 0.f ? 1.f : ed;
    mx = fmaxf(mx, p);
    den = fmaf(den, scale, wgt);
    S1 = fmaf(S1, scale, wgt * xs);
  }
  float T = S1 / den;
  float2 bv = *(const float2*)&bias[c];
  float o0 = fmaxf(fmaf(wl.x, T, bl2.x + bv.x), 0.f);
  float o1 = fmaxf(fmaf(wl.y, T, bl2.y + bv.y), 0.f);
  *(float2*)&outh[(size_t)t * HCC + c] = make_float2(o0, o1);
}

// ---------------- GATv2 layer 2: one wave per node, online softmax ----------------
// Single pass over edges (was two): one 512B gather per edge instead of two,
// with explicit next-edge prefetch to keep 2 gathers in flight per wave.
__global__ void gat2_kernel(const float* __restrict__ xl, const float* __restrict__ xr,
    const int* __restrict__ offs, const int* __restrict__ csr_src,
    const float* __restrict__ csr_ea,
    const float* __restrict__ We, const float* __restrict__ att,
    const float* __restrict__ bias, float* __restrict__ outh, int N) {
  int t = (blockIdx.x * blockDim.x + threadIdx.x) >> 6;
  if (t >= N) return;
  int lane = threadIdx.x & 63;
  int c = lane * 2;
  float2 xrv = *(const float2*)&xr[(size_t)t * HCC + c];
  float2 wev = *(const float2*)&We[c];
  float2 atv = *(const float2*)&att[c];
  int e0 = offs[t], e1 = offs[t + 1];

  float mx = -1e30f, den = 0.f, a0 = 0.f, a1 = 0.f;
  float ean = csr_ea[e0];
  float2 xjn = *(const float2*)&xl[(size_t)csr_src[e0] * HCC + c];
  for (int e = e0; e < e1; e++) {
    float2 xj = xjn; float eav = ean;
    if (e + 1 < e1) {             // prefetch next edge's gather
      int s2 = csr_src[e + 1];
      ean = csr_ea[e + 1];
      xjn = *(const float2*)&xl[(size_t)s2 * HCC + c];
    }
    float m0 = fmaf(eav, wev.x, xrv.x + xj.x);
    float m1 = fmaf(eav, wev.y, xrv.y + xj.y);
    m0 = m0 > 0.f ? m0 : NEG_SLOPE * m0;
    m1 = m1 > 0.f ? m1 : NEG_SLOPE * m1;
    float p = fmaf(m0, atv.x, m1 * atv.y);
    #pragma unroll
    for (int off = 1; off < 32; off <<= 1) p += __shfl_xor(p, off);
    float d = p - mx;
    float ed = __expf(-fabsf(d));
    float scale = d > 0.f ? ed : 1.f;
    float wgt = d > 0.f ? 1.f : ed;
    mx = fmaxf(mx, p);
    den = fmaf(den, scale, wgt);
    a0 = fmaf(a0, scale, wgt * xj.x);
    a1 = fmaf(a1, scale, wgt * xj.y);
  }
  float inv = 1.0f / den;
  float2 bv = *(const float2*)&bias[c];
  float o0 = fmaxf(fmaf(a0, inv, bv.x), 0.f);
  float o1 = fmaxf(fmaf(a1, inv, bv.y), 0.f);
  *(float2*)&outh[(size_t)t * HCC + c] = make_float2(o0, o1);
}

// ---------------- layer-2 transforms: h1(N,128) @ {Wl,Wr}(128,128) ----------------
__global__ __launch_bounds__(256) void l2_transform_kernel(const float* __restrict__ h,
    const float* __restrict__ Wl, const float* __restrict__ bl,
    const float* __restrict__ Wr, const float* __restrict__ br,
    float* __restrict__ xl, float* __restrict__ xr, int N) {
  __shared__ float hs[16][HCC];
  __shared__ float Ws[2][32][HCC];
  int tid = threadIdx.x;
  int nbase = blockIdx.x * 16;
  for (int i = tid; i < 16 * 32; i += 256) {
    int nr = i >> 5, col = (i & 31) * 4;
    int gn = nbase + nr;
    float4 v = (gn < N) ? *(const float4*)&h[(size_t)gn * HCC + col] : make_float4(0,0,0,0);
    *(float4*)&hs[nr][col] = v;
  }
  int slot = tid >> 5;
  int c0 = (tid & 31) * 4;
  float acc[2][8];
  #pragma unroll
  for (int s = 0; s < 2; s++)
    #pragma unroll
    for (int q = 0; q < 8; q++) acc[s][q] = 0.f;

  for (int kb = 0; kb < 4; kb++) {
    __syncthreads();
    for (int i = tid; i < 2048; i += 256) {
      int mat = i >> 10;
      int idx = i & 1023;
      int krow = idx >> 5, col = (idx & 31) * 4;
      const float* src = mat ? Wr : Wl;
      *(float4*)&Ws[mat][krow][col] = *(const float4*)&src[(size_t)(kb * 32 + krow) * HCC + col];
    }
    __syncthreads();
    for (int k2 = 0; k2 < 32; k2++) {
      float4 wl4 = *(const float4*)&Ws[0][k2][c0];
      float4 wr4 = *(const float4*)&Ws[1][k2][c0];
      int kk = kb * 32 + k2;
      #pragma unroll
      for (int s = 0; s < 2; s++) {
        float hv = hs[slot + 8 * s][kk];
        acc[s][0] = fmaf(hv, wl4.x, acc[s][0]);
        acc[s][1] = fmaf(hv, wl4.y, acc[s][1]);
        acc[s][2] = fmaf(hv, wl4.z, acc[s][2]);
        acc[s][3] = fmaf(hv, wl4.w, acc[s][3]);
        acc[s][4] = fmaf(hv, wr4.x, acc[s][4]);
        acc[s][5] = fmaf(hv, wr4.y, acc[s][5]);
        acc[s][6] = fmaf(hv, wr4.z, acc[s][6]);
        acc[s][7] = fmaf(hv, wr4.w, acc[s][7]);
      }
    }
  }
  float4 blv = *(const float4*)&bl[c0];
  float4 brv = *(const float4*)&br[c0];
  #pragma unroll
  for (int s = 0; s < 2; s++) {
    int gn = nbase + slot + 8 * s;
    if (gn < N) {
      float4 o1 = make_float4(acc[s][0] + blv.x, acc[s][1] + blv.y, acc[s][2] + blv.z, acc[s][3] + blv.w);
      float4 o2 = make_float4(acc[s][4] + brv.x, acc[s][5] + brv.y, acc[s][6] + brv.z, acc[s][7] + brv.w);
      *(float4*)&xl[(size_t)gn * HCC + c0] = o1;
      *(float4*)&xr[(size_t)gn * HCC + c0] = o2;
    }
  }
}

// ---------------- msg_emb^T = (message @ fc1_W + fc1_b)^T  -> [128][256] ----------------
__global__ void msg_gemm_kernel(const float* __restrict__ msg, const float* __restrict__ W,
                                const float* __restrict__ b, float* __restrict__ memb_t) {
  int r = blockIdx.x, c = threadIdx.x;  // r = message index (0..255), c = out channel (0..127)
  const float* mrow = &msg[(size_t)r * HCC];
  float acc = b[c];
  #pragma unroll 8
  for (int k = 0; k < HCC; k++) acc = fmaf(mrow[k], W[(size_t)k * HCC + c], acc);
  memb_t[(size_t)c * 256 + r] = acc;
}

// ---------------- logits = h @ memb^T; row softmax ----------------
__global__ __launch_bounds__(256) void logits_softmax_kernel(
    const float* __restrict__ h, const float* __restrict__ memb_t,
    float* __restrict__ out, int N) {
  __shared__ float hs[64][HCC];   // 32 KB
  __shared__ float ms[32][256];   // 32 KB  (k-chunk of memb_t)
  int tid = threadIdx.x;
  int nbase = blockIdx.x * 64;
  for (int i = tid; i < 64 * 32; i += 256) {
    int nr = i >> 5, col = (i & 31) * 4;
    int gn = nbase + nr;
    float4 v = (gn < N) ? *(const float4*)&h[(size_t)gn * HCC + col] : make_float4(0, 0, 0, 0);
    *(float4*)&hs[nr][col] = v;
  }
  int ty = tid >> 5, tx = tid & 31;
  float acc[8][8];
  #pragma unroll
  for (int i = 0; i < 8; i++)
    #pragma unroll
    for (int j = 0; j < 8; j++) acc[i][j] = 0.f;

  for (int kb = 0; kb < 4; kb++) {
    __syncthreads();
    for (int i = tid; i < 2048; i += 256) {
      int kr = i >> 6, col = (i & 63) * 4;
      *(float4*)&ms[kr][col] = *(const float4*)&memb_t[(size_t)(kb * 32 + kr) * 256 + col];
    }
    __syncthreads();
    for (int kk = 0; kk < 32; kk += 4) {
      float4 a[8];
      #pragma unroll
      for (int i = 0; i < 8; i++) a[i] = *(const float4*)&hs[ty * 8 + i][kb * 32 + kk];
      #pragma unroll
      for (int q = 0; q < 4; q++) {
        float bv[8];
        #pragma unroll
        for (int j = 0; j < 8; j++) bv[j] = ms[kk + q][j * 32 + tx];
        #pragma unroll
        for (int i = 0; i < 8; i++) {
          float av = (q == 0) ? a[i].x : (q == 1) ? a[i].y : (q == 2) ? a[i].z : a[i].w;
          #pragma unroll
          for (int j = 0; j < 8; j++) acc[i][j] = fmaf(av, bv[j], acc[i][j]);
        }
      }
    }
  }

  #pragma unroll
  for (int i = 0; i < 8; i++) {
    int gn = nbase + ty * 8 + i;
    float m = acc[i][0];
    #pragma unroll
    for (int j = 1; j < 8; j++) m = fmaxf(m, acc[i][j]);
    #pragma unroll
    for (int off = 1; off < 32; off <<= 1) m = fmaxf(m, __shfl_xor(m, off));
    float e[8], s = 0.f;
    #pragma unroll
    for (int j = 0; j < 8; j++) { e[j] = expf(acc[i][j] - m); s += e[j]; }
    #pragma unroll
    for (int off = 1; off < 32; off <<= 1) s += __shfl_xor(s, off);
    float inv = 1.0f / s;
    if (gn < N) {
      #pragma unroll
      for (int j = 0; j < 8; j++) out[(size_t)gn * 256 + j * 32 + tx] = e[j] * inv;
    }
  }
}

extern "C" void kernel_launch(void* const* d_in, const int* in_sizes, int n_in,
                              void* d_out, int out_size, void* d_ws, size_t ws_size,
                              hipStream_t stream) {
  (void)n_in; (void)out_size; (void)ws_size;
  const float* message  = (const float*)d_in[0];
  const float* x        = (const float*)d_in[1];
  const float* edge_attr= (const float*)d_in[2];
  const float* c1_Wl   = (const float*)d_in[3];
  const float* c1_bl   = (const float*)d_in[4];
  const float* c1_Wr   = (const float*)d_in[5];
  const float* c1_br   = (const float*)d_in[6];
  const float* c1_We   = (const float*)d_in[7];
  const float* c1_att  = (const float*)d_in[8];
  const float* c1_bias = (const float*)d_in[9];
  const float* c2_Wl   = (const float*)d_in[10];
  const float* c2_bl   = (const float*)d_in[11];
  const float* c2_Wr   = (const float*)d_in[12];
  const float* c2_br   = (const float*)d_in[13];
  const float* c2_We   = (const float*)d_in[14];
  const float* c2_att  = (const float*)d_in[15];
  const float* c2_bias = (const float*)d_in[16];
  const float* fc1_W   = (const float*)d_in[17];
  const float* fc1_b   = (const float*)d_in[18];
  const int* edge_index = (const int*)d_in[19];

  const int N = in_sizes[1];          // 50000
  const int E = in_sizes[2];          // 500000
  const int Et = E + N;
  const int B = in_sizes[0] / HCC;    // 256
  float* out = (float*)d_out;

  char* wsb = (char*)d_ws;
  size_t woff = 0;
  auto alloc = [&](size_t bytes) -> void* {
    void* p = wsb + woff;
    woff += (bytes + 255) & ~(size_t)255;
    return p;
  };
  float* xl     = (float*)alloc((size_t)N * HCC * 4);
  float* xr     = (float*)alloc((size_t)N * HCC * 4);
  float* hb     = (float*)alloc((size_t)N * HCC * 4);
  float* memb_t = (float*)alloc((size_t)B * HCC * 4);
  float* ea_sum = (float*)alloc(256);
  int* deg      = (int*)alloc((size_t)N * 4);
  int* offs     = (int*)alloc((size_t)(N + 1) * 4);
  int* cursor   = (int*)alloc((size_t)N * 4);
  int* csr_src  = (int*)alloc((size_t)Et * 4);
  float* csr_ea = (float*)alloc((size_t)Et * 4);

  hipMemsetAsync(ea_sum, 0, 4, stream);
  hipMemsetAsync(deg, 0, (size_t)N * 4, stream);
  hipMemsetAsync(cursor, 0, (size_t)N * 4, stream);

  ea_reduce_kernel<<<256, 256, 0, stream>>>(edge_attr, ea_sum, E);
  deg_count_kernel<<<(Et + 255) / 256, 256, 0, stream>>>(edge_index, deg, E, N);
  scan_kernel<<<1, 1024, 0, stream>>>(deg, offs, N);
  scatter_kernel<<<(Et + 255) / 256, 256, 0, stream>>>(edge_index, edge_attr, ea_sum,
                                                       offs, cursor, csr_src, csr_ea, E, N);
  gat1_kernel<<<(N + 3) / 4, 256, 0, stream>>>(x, offs, csr_src, csr_ea,
                                               c1_Wl, c1_bl, c1_Wr, c1_br,
                                               c1_We, c1_att, c1_bias, hb, N);
  l2_transform_kernel<<<(N + 15) / 16, 256, 0, stream>>>(hb, c2_Wl, c2_bl, c2_Wr, c2_br,
                                                         xl, xr, N);
  gat2_kernel<<<(N + 3) / 4, 256, 0, stream>>>(xl, xr, offs, csr_src, csr_ea,
                                               c2_We, c2_att, c2_bias, hb, N);
  msg_gemm_kernel<<<B, HCC, 0, stream>>>(message, fc1_W, fc1_b, memb_t);
  logits_softmax_kernel<<<(N + 63) / 64, 256, 0, stream>>>(hb, memb_t, out, N);
}